// Round 4
// baseline (204.588 us; speedup 1.0000x reference)
//
#include <hip/hip_runtime.h>
#include <math.h>

// Problem constants (reference: B=4, N=2048, TIMESTEPS=1000, speed=0.01)
#define TIMESTEPS 1000
constexpr int Bc = 4;
constexpr int Nc = 2048;
constexpr int EcI = Nc * (Nc - 1) / 2;   // 2,096,128
// Row-pairing: virtual row r in [0,1024) has width 2047:
//   c <  r : (i,j) = (r, c)            [real row r, length r]
//   c >= r : (i,j) = (2047-r, c-r)     [real row 2047-r, length 2047-r]
// Consecutive g -> consecutive c -> consecutive j -> unit-stride loads on
// adj, u, AND q (e = tri(i)+j is consecutive too). Perfectly balanced.
constexpr int VW = Nc - 1;               // 2047 virtual row width
constexpr int PerB = 1024 * VW;          // 2,096,128 == EcI
constexpr int Total = Bc * PerB;         // 8,384,512 = 32752 * 256

__global__ __launch_bounds__(256) void diff_loss_kernel(
    const int* __restrict__ adj, const int* __restrict__ t,
    const float* __restrict__ u, const float* __restrict__ q,
    double* __restrict__ partials)
{
    __shared__ float tab[Bc][8];
    if (threadIdx.x < Bc) {
        int b = threadIdx.x;
        int tb = t[b];
        // Qt[k] built with ts=k+1: flip = 0.5*(1 - 0.98^(k+1))
        float f_t = 0.5f * (1.0f - powf(0.98f, (float)(tb + 1)));
        int tpe = (tb == 0) ? TIMESTEPS : tb;        // Qt[t-1], wrap -1 -> 999
        float f_p = 0.5f * (1.0f - powf(0.98f, (float)tpe));
        float f0  = 0.5f * (1.0f - 0.98f);           // Qt[0] flip
        float omf_t = 1.0f - f_t;
        tab[b][0] = f_t;        // probs1 when a0==0
        tab[b][1] = omf_t;      // probs1 when a0==1
        // q_target(a0,x) = lik1(x)*pri1(a0)/evid(a0,x); evid=(x==a0)?1-f_t:f_t
        tab[b][2] = f0          * f_p          / omf_t;  // a0=0,x=0
        tab[b][3] = (1.0f - f0) * f_p          / f_t;    // a0=0,x=1
        tab[b][4] = f0          * (1.0f - f_p) / f_t;    // a0=1,x=0
        tab[b][5] = (1.0f - f0) * (1.0f - f_p) / omf_t;  // a0=1,x=1
    }
    __syncthreads();

    const int g = blockIdx.x * blockDim.x + threadIdx.x;   // < Total exactly
    int b   = g / PerB;                    // constant divisor -> magic mul
    int rem = g - b * PerB;
    int r   = rem / VW;                    // constant divisor -> magic mul
    int c   = rem - r * VW;

    bool lo = (c < r);
    int i = lo ? r : (Nc - 1) - r;
    int j = lo ? c : c - r;

    int mbase = (b << 22) + (i << 11) + j;             // (b,i,j) in N*N arrays
    int e     = ((i * (i - 1)) >> 1) + j;              // packed tri index

    int   a0 = adj[mbase];
    float uu = u[mbase];
    float qv = q[b * EcI + e];

    float p0   = tab[b][0], p1   = tab[b][1];
    float qt00 = tab[b][2], qt01 = tab[b][3];
    float qt10 = tab[b][4], qt11 = tab[b][5];

    float ps  = a0 ? p1 : p0;
    bool  x   = (uu < ps);
    float t0  = x ? qt01 : qt00;
    float t1  = x ? qt11 : qt10;
    float qtv = a0 ? t1 : t0;
    float s = fmaxf(qv, 0.0f) - qv * qtv + __logf(1.0f + __expf(-fabsf(qv)));

    double acc = (double)s;
    // wave (64) shuffle reduce, then cross-wave via LDS
    for (int off = 32; off > 0; off >>= 1)
        acc += __shfl_down(acc, off, 64);
    __shared__ double wsum[4];
    int lane = threadIdx.x & 63, wid = threadIdx.x >> 6;
    if (lane == 0) wsum[wid] = acc;
    __syncthreads();
    if (threadIdx.x == 0)
        partials[blockIdx.x] = wsum[0] + wsum[1] + wsum[2] + wsum[3];
}

// Reduce per-block partials, write mean as f32.
__global__ __launch_bounds__(256) void final_reduce_kernel(
    const double* __restrict__ partials, int nb, float* __restrict__ out)
{
    double acc = 0.0;
    for (int idx = threadIdx.x; idx < nb; idx += blockDim.x)
        acc += partials[idx];
    for (int off = 32; off > 0; off >>= 1)
        acc += __shfl_down(acc, off, 64);
    __shared__ double wsum[4];
    int lane = threadIdx.x & 63, wid = threadIdx.x >> 6;
    if (lane == 0) wsum[wid] = acc;
    __syncthreads();
    if (threadIdx.x == 0)
        out[0] = (float)((wsum[0] + wsum[1] + wsum[2] + wsum[3]) /
                         ((double)Bc * (double)EcI));
}

extern "C" void kernel_launch(void* const* d_in, const int* in_sizes, int n_in,
                              void* d_out, int out_size, void* d_ws, size_t ws_size,
                              hipStream_t stream) {
    const int*   adj = (const int*)d_in[0];   // adj_start (B,N,N) int32
    const int*   t   = (const int*)d_in[1];   // t (B,) int32
    const float* u   = (const float*)d_in[2]; // u (B,N,N) f32
    const float* q   = (const float*)d_in[3]; // q_approx (B,E) f32
    float*  out      = (float*)d_out;
    double* partials = (double*)d_ws;         // NB doubles (~262 KB)

    const int NB = Total / 256;               // 32,752 blocks, exact cover
    diff_loss_kernel<<<NB, 256, 0, stream>>>(adj, t, u, q, partials);
    final_reduce_kernel<<<1, 256, 0, stream>>>(partials, NB, out);
}

// Round 5
// 165.255 us; speedup vs baseline: 1.2380x; 1.2380x over previous
//
#include <hip/hip_runtime.h>
#include <math.h>

// Problem constants (reference: B=4, N=2048, TIMESTEPS=1000, speed=0.01)
#define TIMESTEPS 1000
constexpr int Bc = 4;
constexpr int Nc = 2048;
constexpr int EcI = Nc * (Nc - 1) / 2;   // 2,096,128

// Block = one virtual row pair of the strict lower triangle:
//   rows iA = r (length r) and iB = 2047-r (length 2047-r), total 2047 elements.
//   Slot s in [0,2048): s < r -> (iA, s); r <= s < 2047 -> (iB, s-r); s==2047 idle.
// Row bases are block-uniform (scalar regs); per-element cost is ~6 VALU.
// All loads are unit-stride across lanes (256 B per wave instruction).
__global__ __launch_bounds__(256) void diff_loss_kernel(
    const int* __restrict__ adj, const int* __restrict__ t,
    const float* __restrict__ u, const float* __restrict__ q,
    double* __restrict__ partials)
{
    __shared__ float tab[Bc][8];
    if (threadIdx.x < Bc) {
        int b = threadIdx.x;
        int tb = t[b];
        // Qt[k] built with ts=k+1: flip = 0.5*(1 - 0.98^(k+1))
        float f_t = 0.5f * (1.0f - powf(0.98f, (float)(tb + 1)));
        int tpe = (tb == 0) ? TIMESTEPS : tb;        // Qt[t-1], wrap -1 -> 999
        float f_p = 0.5f * (1.0f - powf(0.98f, (float)tpe));
        float f0  = 0.5f * (1.0f - 0.98f);           // Qt[0] flip
        float omf_t = 1.0f - f_t;
        tab[b][0] = f_t;        // probs1 when a0==0
        tab[b][1] = omf_t;      // probs1 when a0==1
        // q_target(a0,x) = lik1(x)*pri1(a0)/evid(a0,x); evid=(x==a0)?1-f_t:f_t
        tab[b][2] = f0          * f_p          / omf_t;  // a0=0,x=0
        tab[b][3] = (1.0f - f0) * f_p          / f_t;    // a0=0,x=1
        tab[b][4] = f0          * (1.0f - f_p) / f_t;    // a0=1,x=0
        tab[b][5] = (1.0f - f0) * (1.0f - f_p) / omf_t;  // a0=1,x=1
    }
    __syncthreads();

    const int bid = blockIdx.x;            // [0, 4096)
    const int b = bid >> 10;               // batch
    const int r = bid & 1023;              // virtual row
    const int iA = r;                      // row A (length r)
    const int iB = (Nc - 1) - r;           // row B (length 2047-r)
    const int mA = (b << 22) + (iA << 11);                 // adj/u row bases
    const int mB = (b << 22) + (iB << 11);
    const int eA = b * EcI + ((iA * (iA - 1)) >> 1);       // q row bases
    const int eB = b * EcI + ((iB * (iB - 1)) >> 1);

    const float p0   = tab[b][0], p1   = tab[b][1];
    const float qt00 = tab[b][2], qt01 = tab[b][3];
    const float qt10 = tab[b][4], qt11 = tab[b][5];

    float sum = 0.0f;
    #pragma unroll
    for (int k = 0; k < 8; ++k) {
        int s = threadIdx.x + (k << 8);
        bool valid = (s < Nc - 1);                 // slot 2047 is idle
        int sc = valid ? s : (Nc - 2);
        bool lo = (sc < r);
        int mAddr = lo ? (mA + sc) : (mB + (sc - r));
        int eAddr = lo ? (eA + sc) : (eB + (sc - r));

        int   a0 = adj[mAddr];
        float uu = u[mAddr];
        float qv = q[eAddr];

        float ps  = a0 ? p1 : p0;
        bool  x   = (uu < ps);
        float t0  = x ? qt01 : qt00;
        float t1  = x ? qt11 : qt10;
        float qtv = a0 ? t1 : t0;
        float l = fmaxf(qv, 0.0f) - qv * qtv + __logf(1.0f + __expf(-fabsf(qv)));
        sum += valid ? l : 0.0f;
    }

    double acc = (double)sum;
    // wave (64) shuffle reduce, then cross-wave via LDS
    for (int off = 32; off > 0; off >>= 1)
        acc += __shfl_down(acc, off, 64);
    __shared__ double wsum[4];
    int lane = threadIdx.x & 63, wid = threadIdx.x >> 6;
    if (lane == 0) wsum[wid] = acc;
    __syncthreads();
    if (threadIdx.x == 0)
        partials[blockIdx.x] = wsum[0] + wsum[1] + wsum[2] + wsum[3];
}

// Reduce per-block partials, write mean as f32.
__global__ __launch_bounds__(256) void final_reduce_kernel(
    const double* __restrict__ partials, int nb, float* __restrict__ out)
{
    double acc = 0.0;
    for (int idx = threadIdx.x; idx < nb; idx += blockDim.x)
        acc += partials[idx];
    for (int off = 32; off > 0; off >>= 1)
        acc += __shfl_down(acc, off, 64);
    __shared__ double wsum[4];
    int lane = threadIdx.x & 63, wid = threadIdx.x >> 6;
    if (lane == 0) wsum[wid] = acc;
    __syncthreads();
    if (threadIdx.x == 0)
        out[0] = (float)((wsum[0] + wsum[1] + wsum[2] + wsum[3]) /
                         ((double)Bc * (double)EcI));
}

extern "C" void kernel_launch(void* const* d_in, const int* in_sizes, int n_in,
                              void* d_out, int out_size, void* d_ws, size_t ws_size,
                              hipStream_t stream) {
    const int*   adj = (const int*)d_in[0];   // adj_start (B,N,N) int32
    const int*   t   = (const int*)d_in[1];   // t (B,) int32
    const float* u   = (const float*)d_in[2]; // u (B,N,N) f32
    const float* q   = (const float*)d_in[3]; // q_approx (B,E) f32
    float*  out      = (float*)d_out;
    double* partials = (double*)d_ws;         // 4096 doubles (32 KB)

    const int NB = Bc * 1024;                 // 4096 blocks, exact cover
    diff_loss_kernel<<<NB, 256, 0, stream>>>(adj, t, u, q, partials);
    final_reduce_kernel<<<1, 256, 0, stream>>>(partials, NB, out);
}